// Round 8
// baseline (60.554 us; speedup 1.0000x reference)
//
#include <hip/hip_runtime.h>

// Problem constants (fixed by setup_inputs)
constexpr int T_TASKS = 256;
constexpr int NQ      = 300;
constexpr int NS      = 25;
constexpr int D       = 640;
constexpr int NWAY    = 5;
constexpr float LAMBDA_REG = 50.0f;

constexpr int SP4 = 161;        // float4 stride of one S row in LDS (644 floats)
constexpr int AC  = NS + NWAY;  // augmented columns = 30
constexpr int ROWS_PER_BLK = 60;
constexpr int CHUNKS = NQ / ROWS_PER_BLK;   // 5 blocks per task in K2

// Pair-block table: 15 upper-triangle 5x5 blocks of the 25x25 Gram matrix
__device__ __constant__ int PA[15] = {0,0,0,0,0,1,1,1,1,2,2,2,3,3,4};
__device__ __constant__ int PB[15] = {0,1,2,3,4,1,2,3,4,2,3,4,3,4,4};

// ---------------------------------------------------------------------------
// R3-R7 lesson: 1024-thread blocks are pinned to 64 VGPR by the allocator
// (spills instead of expanding) AND give only 16 waves/CU. Solution: two
// 256-thread kernels (256T kernels allocate VGPRs freely - m97: 164 - and
// stack 8 blocks/CU for TLP). The wmat global round-trip (3.3MB w + 16.4MB r,
// L2-warm) is the price; 32 streaming waves/CU is the prize.
// ---------------------------------------------------------------------------

// K1: per-task ridge solve -> wmat[t][w][d] in workspace.
__global__ __launch_bounds__(256) void ridge_solve_kernel(
    const float* __restrict__ support,   // (T, NS, D)
    const int*   __restrict__ labels,    // (T, NS)
    float*       __restrict__ wmat)      // (T, NWAY, D)
{
    __shared__ __align__(16) float4 sS4[NS * SP4];   // 64,400 B
    __shared__ float aug[NS][32];
    __shared__ float sX[NS][NWAY];

    const int t   = blockIdx.x;
    const int tid = threadIdx.x;
    const float* Sg = support + (size_t)t * NS * D;

    // Stage S into LDS (coalesced float4)
    for (int idx = tid; idx < NS * 160; idx += 256) {
        int s = idx / 160, f = idx % 160;
        sS4[s * SP4 + f] = reinterpret_cast<const float4*>(Sg)[idx];
    }
    if (tid < NS * NWAY) {              // RHS = 2 * onehot
        int s = tid / NWAY, w = tid % NWAY;
        aug[s][NS + w] = (labels[t * NS + s] == w) ? 2.0f : 0.0f;
    }
    __syncthreads();

    // Gram: K = S S^T + lambda I, 15 pair-blocks x 16 lanes (threads 0..239).
    // B row reloaded per-j to keep peak pressure ~55 regs.
    if (tid < 240) {
        const int grp = tid >> 4, l = tid & 15;
        const int ra = PA[grp] * 5, rb = PB[grp] * 5;
        float acc[25] = {};
        #pragma unroll 2
        for (int k = 0; k < 10; ++k) {
            const int f = l + 16 * k;
            float4 A[5];
            #pragma unroll
            for (int r = 0; r < 5; ++r) A[r] = sS4[(ra + r) * SP4 + f];
            #pragma unroll
            for (int j = 0; j < 5; ++j) {
                float4 b = sS4[(rb + j) * SP4 + f];
                #pragma unroll
                for (int i = 0; i < 5; ++i)
                    acc[i * 5 + j] += A[i].x * b.x + A[i].y * b.y +
                                      A[i].z * b.z + A[i].w * b.w;
            }
        }
        #pragma unroll
        for (int p = 0; p < 25; ++p) {
            #pragma unroll
            for (int off = 8; off >= 1; off >>= 1)
                acc[p] += __shfl_xor(acc[p], off);
        }
        if (l == 0) {
            #pragma unroll
            for (int p = 0; p < 25; ++p) {
                int i = ra + p / 5, j = rb + p % 5;
                float v = acc[p] + (i == j ? LAMBDA_REG : 0.0f);
                aug[i][j] = v;
                aug[j][i] = v;
            }
        }
    }
    __syncthreads();

    // Gauss-Jordan in wave-0 registers; lane c owns column c of 25x30 system.
    if (tid < 64) {
        const int  c      = tid;
        const bool active = (c < AC);
        float a[NS];
        #pragma unroll
        for (int r = 0; r < NS; ++r) a[r] = active ? aug[r][c] : 0.0f;
        #pragma unroll
        for (int k = 0; k < NS; ++k) {
            float piv = __shfl(a[k], k);
            float inv = 1.0f / piv;
            a[k] *= inv;
            #pragma unroll
            for (int r = 0; r < NS; ++r) {
                if (r != k) {
                    float m = __shfl(a[r], k);
                    a[r] -= m * a[k];
                }
            }
        }
        if (active && c >= NS) {        // RHS columns hold X = 2 K^-1 Y
            const int w = c - NS;
            #pragma unroll
            for (int s = 0; s < NS; ++s) sX[s][w] = a[s];
        }
    }
    __syncthreads();

    // W[w][d] = sum_s S[s][d] * X[s][w]; threads cover d = tid + 256*ii.
    const float* sSf = reinterpret_cast<const float*>(sS4);
    #pragma unroll
    for (int ii = 0; ii < 3; ++ii) {
        const int d = tid + 256 * ii;
        if (d < D) {
            float acc[NWAY] = {};
            #pragma unroll
            for (int s = 0; s < NS; ++s) {
                float sv = sSf[s * (SP4 * 4) + d];
                #pragma unroll
                for (int w = 0; w < NWAY; ++w) acc[w] += sv * sX[s][w];
            }
            #pragma unroll
            for (int w = 0; w < NWAY; ++w)
                wmat[((size_t)t * NWAY + w) * D + d] = acc[w];
        }
    }
}

// K2: logits = scale * Q W. Grid 1280 (5 blocks/task), 256 threads,
// 16 groups x 16 lanes, 60 rows/block, 1 row per round (R2's spill-safe
// pattern: 10 float4 in flight, ~55 live regs), last round exec-masked.
__global__ __launch_bounds__(256) void logits_kernel(
    const float* __restrict__ query,   // (T, NQ, D)
    const float* __restrict__ wmat,    // (T, NWAY, D)
    const float* __restrict__ scale,   // (1,)
    float*       __restrict__ out)     // (T, NQ, NWAY)
{
    __shared__ __align__(16) float sW[NWAY][D];   // 12,800 B -> 8 blocks/CU

    const int b     = blockIdx.x;
    const int t     = b / CHUNKS;
    const int chunk = b % CHUNKS;
    const int tid   = threadIdx.x;

    for (int idx = tid; idx < NWAY * D / 4; idx += 256)
        reinterpret_cast<float4*>(&sW[0][0])[idx] =
            reinterpret_cast<const float4*>(wmat + (size_t)t * NWAY * D)[idx];
    __syncthreads();

    const float sc = scale[0];
    const int g  = tid >> 4;            // 16 groups
    const int l4 = tid & 15;
    const float4* Qb4 = reinterpret_cast<const float4*>(query + (size_t)t * NQ * D);
    const int row0 = chunk * ROWS_PER_BLK;

    #pragma unroll
    for (int j = 0; j < 4; ++j) {       // rounds: rows g, g+16, g+32, g+48
        const int  r  = j * 16 + g;     // 0..63
        const bool ok = (r < ROWS_PER_BLK);     // exec-masked tail (r<60)
        const int  q  = row0 + r;
        const int  off = q * 160 + l4;
        float acc[NWAY] = {};
        if (ok) {
            #pragma unroll
            for (int i = 0; i < 10; ++i) {      // 10 float4 in flight
                float4 qv = Qb4[off + i * 16];
                const int dbase = i * 64 + 4 * l4;
                #pragma unroll
                for (int w = 0; w < NWAY; ++w) {
                    const float4 wv = *reinterpret_cast<const float4*>(&sW[w][dbase]);
                    acc[w] += qv.x * wv.x + qv.y * wv.y + qv.z * wv.z + qv.w * wv.w;
                }
            }
        }
        #pragma unroll
        for (int w = 0; w < NWAY; ++w) {
            #pragma unroll
            for (int o = 8; o >= 1; o >>= 1)
                acc[w] += __shfl_xor(acc[w], o);
        }
        float ov = acc[0];
        ov = (l4 == 1) ? acc[1] : ov;
        ov = (l4 == 2) ? acc[2] : ov;
        ov = (l4 == 3) ? acc[3] : ov;
        ov = (l4 == 4) ? acc[4] : ov;
        if (ok && l4 < NWAY)
            out[((size_t)t * NQ + q) * NWAY + l4] = sc * ov;
    }
}

extern "C" void kernel_launch(void* const* d_in, const int* in_sizes, int n_in,
                              void* d_out, int out_size, void* d_ws, size_t ws_size,
                              hipStream_t stream) {
    const float* query   = (const float*)d_in[0];
    const float* support = (const float*)d_in[1];
    const float* scale   = (const float*)d_in[2];
    const int*   labels  = (const int*)d_in[3];

    float* wmat = (float*)d_ws;          // T*NWAY*D*4 = 3,276,800 B
    float* out  = (float*)d_out;

    ridge_solve_kernel<<<T_TASKS, 256, 0, stream>>>(support, labels, wmat);
    logits_kernel<<<T_TASKS * CHUNKS, 256, 0, stream>>>(query, wmat, scale, out);
}